// Round 11
// baseline (70.065 us; speedup 1.0000x reference)
//
#include <hip/hip_runtime.h>
#include <math.h>

#define BB 64
#define HH 512
#define WW 512
#define HWQ (HH*WW)
#define NTOT ((size_t)BB*HWQ)

// ws layout:
//  [0, 2MB)  : target bitmask, 1 bit/px (word w covers px 32w..32w+31)
//  then doubles:
//   [0..63]      a_c slots (k_fused atomics; zeroed by k_bits block 0)
//   [64+8b+0,1]  TP_b, sumP_b (k_fused atomics; zeroed by k_bits block 0)
//   [576+blk]    k_bits per-block t-count partials (plain stores)
#define BITS_BYTES (NTOT / 8)
#define ACC_MAIN_DOUBLES 576

// target f32 -> bitmask + per-block t-count. 2048 blocks, 32 px/thread.
__global__ __launch_bounds__(256) void k_bits(const float* __restrict__ tgt,
                                              unsigned* __restrict__ bits,
                                              double* __restrict__ accz,
                                              double* __restrict__ tpart) {
  if (blockIdx.x == 0) {
    for (int i = threadIdx.x; i < ACC_MAIN_DOUBLES; i += 256) accz[i] = 0.0;
  }
  size_t base = (size_t)blockIdx.x * 8192 + (size_t)threadIdx.x * 32;
  const float* p = tgt + base;
  unsigned wrd = 0u;
#pragma unroll
  for (int k = 0; k < 8; ++k) {
    const float4 t = *(const float4*)(p + 4 * k);
    wrd |= ((__float_as_uint(t.x) >> 29) & 1u) << (4 * k + 0);   // 1.0f -> 1, 0.0f -> 0
    wrd |= ((__float_as_uint(t.y) >> 29) & 1u) << (4 * k + 1);
    wrd |= ((__float_as_uint(t.z) >> 29) & 1u) << (4 * k + 2);
    wrd |= ((__float_as_uint(t.w) >> 29) & 1u) << (4 * k + 3);
  }
  bits[(size_t)blockIdx.x * 256 + threadIdx.x] = wrd;
  int cnt = __popc(wrd);
#pragma unroll
  for (int o = 32; o > 0; o >>= 1) cnt += __shfl_down(cnt, o, 64);
  __shared__ int s_t[4];
  int wv = threadIdx.x >> 6, lane = threadIdx.x & 63;
  if (lane == 0) s_t[wv] = cnt;
  __syncthreads();
  if (threadIdx.x == 0)
    tpart[blockIdx.x] = (double)(s_t[0] + s_t[1] + s_t[2] + s_t[3]);
}

__device__ inline float wredf(float v) {
#pragma unroll
  for (int o = 32; o > 0; o >>= 1) v += __shfl_down(v, o, 64);
  return v;
}

// masked bit-word load (row-ok wave-uniform, w per-lane)
__device__ inline unsigned ldw(const unsigned* __restrict__ rowp, bool rok, int w) {
  unsigned v = 0u;
  if (rok && w >= 0 && w < 16) v = rowp[w];
  return v;
}

// 40-bit window: bit k <-> image col x0-16+k (cols OOB = 0). Valid k: 0..39+.
__device__ inline unsigned long long win40f(const unsigned* __restrict__ bimg,
                                            int r, int w, int rem, bool rok) {
  const unsigned* rowp = bimg + r * 16;
  unsigned A = ldw(rowp, rok, w - 1);
  unsigned B = ldw(rowp, rok, w);
  unsigned C = ldw(rowp, rok, w + 1);
  unsigned long long lo = (((unsigned long long)B) << 32) | (unsigned long long)A;
  unsigned long long hi = (((unsigned long long)C) << 32) | (unsigned long long)B;
  return (rem < 16) ? (lo >> (rem + 16)) : (hi >> (rem - 16));
}

// one output column j (0..7): u/vv window idx k=j..j+2, t bit k=j+1, box reg BX
#define STEP(J, UM, UP, VM, VC, VP, TCI, PV, BX) do {                 \
    int gx = (UP) - (UM);                                             \
    int gy = (VM) + 2*(VC) + (VP) - 4;                                \
    float tb = __builtin_amdgcn_sqrtf((float)(gx*gx + gy*gy) + 1e-12f); \
    float qq = (TCI) ? (PV) : 1.f - (PV);                             \
    float lg = __log2f(qq);                                           \
    int   di = (TCI) ? (961 - (BX)) : (BX);                           \
    float wgt = fmaf(5.f, tb, fmaf(1.5608741e-3f, (float)di, 0.8f));  \
    a_c = fmaf(wgt, lg, a_c);                                         \
    a_pt += (TCI) ? (PV) : 0.f;                                       \
    a_p  += (PV);                                                     \
    BX += __popc((unsigned)(win_in  >> ((J)+1)) & 0x7FFFFFFFu)        \
        - __popc((unsigned)(win_out >> ((J)+1)) & 0x7FFFFFFFu);       \
  } while (0)

// fused kernel: thread = 8 cols x 16 rows strip; box counts in registers via
// popcount sliding; Sobel from rolling 3-row 10-bit windows. No LDS staging.
__global__ __launch_bounds__(256) void k_fused(const float* __restrict__ pred,
                                               const unsigned* __restrict__ bits,
                                               double* __restrict__ acc) {
  __shared__ float s_red[4][3];
  int blk  = blockIdx.x;           // 512 = 64 images x 8 bands
  int b    = blk >> 3;
  int band = blk & 7;
  int tid  = threadIdx.x;
  int wv   = tid >> 6, lane = tid & 63;
  int x0   = lane * 8;
  int ys   = band * 64 + wv * 16;
  int w    = x0 >> 5;
  int rem  = x0 & 31;

  const unsigned* bimg = bits + (size_t)b * (HWQ / 32);
  const float* prow = pred + (size_t)b * HWQ + (size_t)ys * WW + x0;

  // box init: rows ys-15 .. ys+15 (wave-uniform row bounds)
  int b0=0,b1=0,b2=0,b3=0,b4=0,b5=0,b6=0,b7=0;
  for (int r = ys - 15; r <= ys + 15; ++r) {
    bool rok = (r >= 0) && (r < HH);
    unsigned long long win = win40f(bimg, r, w, rem, rok);
    b0 += __popc((unsigned)(win >> 1) & 0x7FFFFFFFu);
    b1 += __popc((unsigned)(win >> 2) & 0x7FFFFFFFu);
    b2 += __popc((unsigned)(win >> 3) & 0x7FFFFFFFu);
    b3 += __popc((unsigned)(win >> 4) & 0x7FFFFFFFu);
    b4 += __popc((unsigned)(win >> 5) & 0x7FFFFFFFu);
    b5 += __popc((unsigned)(win >> 6) & 0x7FFFFFFFu);
    b6 += __popc((unsigned)(win >> 7) & 0x7FFFFFFFu);
    b7 += __popc((unsigned)(win >> 8) & 0x7FFFFFFFu);
  }
  // Sobel rolling 10-bit windows (bit k <-> col x0-1+k), rows ys-1 and ys
  unsigned s_m = (unsigned)(win40f(bimg, ys - 1, w, rem, ys >= 1) >> 15) & 0x3FFu;
  unsigned s_z = (unsigned)(win40f(bimg, ys,     w, rem, true)    >> 15) & 0x3FFu;

  float a_c = 0.f, a_pt = 0.f, a_p = 0.f;
#pragma unroll 2
  for (int y = ys; y < ys + 16; ++y) {
    float4 pA = *(const float4*)prow;
    float4 pB = *(const float4*)(prow + 4);
    prow += WW;
    unsigned s_q = (unsigned)(win40f(bimg, y + 1, w, rem, (y + 1) < HH) >> 15) & 0x3FFu;
    unsigned long long win_in  = win40f(bimg, y + 16, w, rem, (y + 16) < HH);
    unsigned long long win_out = win40f(bimg, y - 15, w, rem, (y - 15) >= 0);

    // u = m+2z+q (0..4), vv = q-m+1 (0..2) per window col k (0..9)
    int u0 = (int)((s_m>>0)&1u) + 2*(int)((s_z>>0)&1u) + (int)((s_q>>0)&1u);
    int u1 = (int)((s_m>>1)&1u) + 2*(int)((s_z>>1)&1u) + (int)((s_q>>1)&1u);
    int u2 = (int)((s_m>>2)&1u) + 2*(int)((s_z>>2)&1u) + (int)((s_q>>2)&1u);
    int u3 = (int)((s_m>>3)&1u) + 2*(int)((s_z>>3)&1u) + (int)((s_q>>3)&1u);
    int u4 = (int)((s_m>>4)&1u) + 2*(int)((s_z>>4)&1u) + (int)((s_q>>4)&1u);
    int u5 = (int)((s_m>>5)&1u) + 2*(int)((s_z>>5)&1u) + (int)((s_q>>5)&1u);
    int u6 = (int)((s_m>>6)&1u) + 2*(int)((s_z>>6)&1u) + (int)((s_q>>6)&1u);
    int u7 = (int)((s_m>>7)&1u) + 2*(int)((s_z>>7)&1u) + (int)((s_q>>7)&1u);
    int u8 = (int)((s_m>>8)&1u) + 2*(int)((s_z>>8)&1u) + (int)((s_q>>8)&1u);
    int u9 = (int)((s_m>>9)&1u) + 2*(int)((s_z>>9)&1u) + (int)((s_q>>9)&1u);
    int vv0 = (int)((s_q>>0)&1u) - (int)((s_m>>0)&1u) + 1;
    int vv1 = (int)((s_q>>1)&1u) - (int)((s_m>>1)&1u) + 1;
    int vv2 = (int)((s_q>>2)&1u) - (int)((s_m>>2)&1u) + 1;
    int vv3 = (int)((s_q>>3)&1u) - (int)((s_m>>3)&1u) + 1;
    int vv4 = (int)((s_q>>4)&1u) - (int)((s_m>>4)&1u) + 1;
    int vv5 = (int)((s_q>>5)&1u) - (int)((s_m>>5)&1u) + 1;
    int vv6 = (int)((s_q>>6)&1u) - (int)((s_m>>6)&1u) + 1;
    int vv7 = (int)((s_q>>7)&1u) - (int)((s_m>>7)&1u) + 1;
    int vv8 = (int)((s_q>>8)&1u) - (int)((s_m>>8)&1u) + 1;
    int vv9 = (int)((s_q>>9)&1u) - (int)((s_m>>9)&1u) + 1;
    int t0 = (int)((s_z>>1)&1u), t1 = (int)((s_z>>2)&1u), t2 = (int)((s_z>>3)&1u), t3 = (int)((s_z>>4)&1u);
    int t4 = (int)((s_z>>5)&1u), t5 = (int)((s_z>>6)&1u), t6 = (int)((s_z>>7)&1u), t7 = (int)((s_z>>8)&1u);

    STEP(0, u0, u2, vv0, vv1, vv2, t0, pA.x, b0);
    STEP(1, u1, u3, vv1, vv2, vv3, t1, pA.y, b1);
    STEP(2, u2, u4, vv2, vv3, vv4, t2, pA.z, b2);
    STEP(3, u3, u5, vv3, vv4, vv5, t3, pA.w, b3);
    STEP(4, u4, u6, vv4, vv5, vv6, t4, pB.x, b4);
    STEP(5, u5, u7, vv5, vv6, vv7, t5, pB.y, b5);
    STEP(6, u6, u8, vv6, vv7, vv8, t6, pB.z, b6);
    STEP(7, u7, u9, vv7, vv8, vv9, t7, pB.w, b7);

    s_m = s_z; s_z = s_q;
  }

  a_c = wredf(a_c); a_pt = wredf(a_pt); a_p = wredf(a_p);
  if (lane == 0) { s_red[wv][0] = a_c; s_red[wv][1] = a_pt; s_red[wv][2] = a_p; }
  __syncthreads();
  if (tid == 0) {
    float rc = 0, rpt = 0, rp = 0;
    for (int w2 = 0; w2 < 4; ++w2) { rc += s_red[w2][0]; rpt += s_red[w2][1]; rp += s_red[w2][2]; }
    atomicAdd(&acc[blk & 63],     (double)rc);
    atomicAdd(&acc[64 + 8*b + 0], (double)rpt);
    atomicAdd(&acc[64 + 8*b + 1], (double)rp);
  }
}

__global__ void k_final(const double* __restrict__ acc, const double* __restrict__ tpart,
                        float* __restrict__ out) {
  int t = threadIdx.x;  // 64 threads = 1 wave; t = image index
  double cs = acc[t];
  double TP = acc[64 + 8*t], Ps = acc[64 + 8*t + 1];
  double Ts = 0.0;
  for (int j = 0; j < 32; ++j) Ts += tpart[t * 32 + j];   // 32 k_bits blocks per image
  double FP = Ps - TP, FN = Ts - TP;
  double tv = (TP + 1e-6) / (TP + 0.3 * FP + 0.7 * FN + 1e-6);
  double om = 1.0 - tv;
  if (om < 0.0) om = 0.0;
  double term = pow(om, 1.0 / 1.33);
#pragma unroll
  for (int o = 32; o > 0; o >>= 1) {
    cs   += __shfl_down(cs, o, 64);
    term += __shfl_down(term, o, 64);
  }
  if (t == 0) {
    double ftl = term / 64.0;
    double n = (double)NTOT;
    out[0] = (float)(ftl - 0.6931471805599453 * cs / n);  // bce = -ln2 * log2(q)
  }
}

extern "C" void kernel_launch(void* const* d_in, const int* in_sizes, int n_in,
                              void* d_out, int out_size, void* d_ws, size_t ws_size,
                              hipStream_t stream) {
  (void)in_sizes; (void)n_in; (void)out_size; (void)ws_size;
  const float* pred = (const float*)d_in[0];
  const float* tgt  = (const float*)d_in[1];
  unsigned* bits = (unsigned*)d_ws;
  double* acc = (double*)((char*)d_ws + BITS_BYTES);
  double* tpart = acc + ACC_MAIN_DOUBLES;

  k_bits<<<(int)(NTOT / 8192), 256, 0, stream>>>(tgt, bits, acc, tpart);
  k_fused<<<BB * 8, 256, 0, stream>>>(pred, bits, acc);
  k_final<<<1, 64, 0, stream>>>(acc, tpart, (float*)d_out);
}

// Round 12
// 62.173 us; speedup vs baseline: 1.1269x; 1.1269x over previous
//
#include <hip/hip_runtime.h>
#include <math.h>

#define BB 64
#define HH 512
#define WW 512
#define HWQ (HH*WW)
#define NTOT ((size_t)BB*HWQ)

// ws layout:
//  [0, 2MB)        : target bitmask, 1 bit/px (word w covers px 32w..32w+31)
//  [2MB, 18MB)     : vt8 per px = vsum(0..31) | t<<5 | t(y-1)<<6 | t(y+1)<<7
//  then doubles:
//   [0..63]      a_c slots (k_main atomics; zeroed by k_bits block 0)
//   [64+8b+0,1]  TP_b, sumP_b (k_main atomics; zeroed by k_bits block 0)
//   [576+blk]    k_bits per-block t-count partials (plain stores)
#define BITS_BYTES (NTOT / 8)
#define ACC_MAIN_DOUBLES 576

// target f32 -> bitmask + per-block t-count. 2048 blocks, 32 px/thread. (R10 proven)
__global__ __launch_bounds__(256) void k_bits(const float* __restrict__ tgt,
                                              unsigned* __restrict__ bits,
                                              double* __restrict__ accz,
                                              double* __restrict__ tpart) {
  if (blockIdx.x == 0) {
    for (int i = threadIdx.x; i < ACC_MAIN_DOUBLES; i += 256) accz[i] = 0.0;
  }
  size_t base = (size_t)blockIdx.x * 8192 + (size_t)threadIdx.x * 32;
  const float* p = tgt + base;
  unsigned wrd = 0u;
#pragma unroll
  for (int k = 0; k < 8; ++k) {
    const float4 t = *(const float4*)(p + 4 * k);
    wrd |= ((__float_as_uint(t.x) >> 29) & 1u) << (4 * k + 0);   // 1.0f -> 1, 0.0f -> 0
    wrd |= ((__float_as_uint(t.y) >> 29) & 1u) << (4 * k + 1);
    wrd |= ((__float_as_uint(t.z) >> 29) & 1u) << (4 * k + 2);
    wrd |= ((__float_as_uint(t.w) >> 29) & 1u) << (4 * k + 3);
  }
  bits[(size_t)blockIdx.x * 256 + threadIdx.x] = wrd;
  int cnt = __popc(wrd);
#pragma unroll
  for (int o = 32; o > 0; o >>= 1) cnt += __shfl_down(cnt, o, 64);
  __shared__ int s_t[4];
  int wv = threadIdx.x >> 6, lane = threadIdx.x & 63;
  if (lane == 0) s_t[wv] = cnt;
  __syncthreads();
  if (threadIdx.x == 0)
    tpart[blockIdx.x] = (double)(s_t[0] + s_t[1] + s_t[2] + s_t[3]);
}

// nibble -> byte-lane spread (bit j of nibble -> byte j)
#define SPL(B) ((((B) & 0xFu) * 0x00204081u) & 0x01010101u)
#define SPH(B) ((((B) >> 4)   * 0x00204081u) & 0x01010101u)

// bits -> vt8. Thread = 8 cols (one byte-col) x 8 rows; SWAR byte box-counters.
// 1024 blocks; bits are L2-resident so the 5x vertical re-read is cheap.
__global__ __launch_bounds__(256) void k_vcol(const unsigned char* __restrict__ bitsb,
                                              unsigned char* __restrict__ vt) {
  int gid = blockIdx.x * 256 + threadIdx.x;   // 262144 = 64 img x 64 bytecol x 64 seg
  int bc  = gid & 63;                         // byte-col (8 cols)
  int seg = (gid >> 6) & 63;                  // 64 segments of 8 rows
  int b   = gid >> 12;
  const unsigned char* bimg = bitsb + (size_t)b * (HWQ / 8);
  unsigned char* vimg = vt + (size_t)b * HWQ;
  int ys = seg * 8;

  unsigned cLo = 0u, cHi = 0u;                // 8 byte-counters (box sums, <=31)
  for (int r = ys - 15; r <= ys + 15; ++r) {
    unsigned v = ((unsigned)r < HH) ? (unsigned)bimg[r * 64 + bc] : 0u;
    cLo += SPL(v); cHi += SPH(v);
  }
  unsigned bm = (ys >= 1) ? (unsigned)bimg[(ys - 1) * 64 + bc] : 0u;
  unsigned bz = (unsigned)bimg[ys * 64 + bc];
  unsigned smLo = SPL(bm), smHi = SPH(bm);
  unsigned szLo = SPL(bz), szHi = SPH(bz);

#pragma unroll 2
  for (int y = ys; y < ys + 8; ++y) {
    unsigned bq = ((unsigned)(y + 1) < HH) ? (unsigned)bimg[(y + 1) * 64 + bc] : 0u;
    unsigned sqLo = SPL(bq), sqHi = SPH(bq);
    unsigned outLo = cLo | (szLo << 5) | (smLo << 6) | (sqLo << 7);
    unsigned outHi = cHi | (szHi << 5) | (smHi << 6) | (sqHi << 7);
    *(uint2*)(vimg + (size_t)y * WW + bc * 8) = make_uint2(outLo, outHi);
    unsigned ba = ((unsigned)(y + 16) < HH) ? (unsigned)bimg[(y + 16) * 64 + bc] : 0u;
    unsigned bs = ((unsigned)(y - 15) < HH) ? (unsigned)bimg[(y - 15) * 64 + bc] : 0u;
    cLo += SPL(ba) - SPL(bs);
    cHi += SPH(ba) - SPH(bs);
    smLo = szLo; smHi = szHi; szLo = sqLo; szHi = sqHi;
  }
}

__device__ inline float wredf(float v) {
#pragma unroll
  for (int o = 32; o > 0; o >>= 1) v += __shfl_down(v, o, 64);
  return v;
}

// 8-byte-granular masked load (col boundaries are 8B-aligned)
__device__ inline uint2 ld8(const unsigned char* __restrict__ row, int off) {
  bool ok = (off >= 0) & (off <= WW - 8);
  int oc = ok ? off : 0;
  uint2 v = *(const uint2*)(row + oc);
  if (!ok) { v.x = 0u; v.y = 0u; }
  return v;
}

__device__ inline int sum4b(unsigned x) {     // sum of the 4 bytes
  unsigned t = (x & 0x00FF00FFu) + ((x >> 8) & 0x00FF00FFu);
  return (int)((t + (t >> 16)) & 0xFFFFu);
}

// window byte I (0..39) <-> col x0-16+I ; I compile-time -> folds to one bfe
#define VTW(I) ((I) < 8  ? (((I)&7) < 4 ? w0.x : w0.y) : \
                (I) < 16 ? (((I)&7) < 4 ? w1.x : w1.y) : \
                (I) < 24 ? (((I)&7) < 4 ? w2.x : w2.y) : \
                (I) < 32 ? (((I)&7) < 4 ? w3.x : w3.y) : \
                           (((I)&7) < 4 ? w4.x : w4.y))
#define BGET5(I) ((int)((VTW(I) >> (((I)&3)*8)) & 31u))   // 5-bit vsum field

// one output column (identical math to R8, which passed)
#define STEP(C, UM, UP, VM, VC, VP, TCI, PV) do {                     \
    int gx = (UP) - (UM);                                             \
    int gy = (VM) + 2*(VC) + (VP) - 4;                                \
    float tb = __builtin_amdgcn_sqrtf((float)(gx*gx + gy*gy) + 1e-12f); \
    float qq = (TCI) ? (PV) : 1.f - (PV);                             \
    float lg = __log2f(qq);                                           \
    int   di = (TCI) ? (961 - sw) : sw;                               \
    float wgt = fmaf(5.f, tb, fmaf(1.5608741e-3f, (float)di, 0.8f));  \
    a_c = fmaf(wgt, lg, a_c);                                         \
    a_pt += (TCI) ? (PV) : 0.f;                                       \
    a_p  += (PV);                                                     \
    sw += BGET5((C)+32) - BGET5((C)+1);                               \
  } while (0)

// main fused kernel (R8-verbatim): reads ONLY pred f32 + vt8 row windows.
__global__ __launch_bounds__(256) void k_main(const float* __restrict__ pred,
                                              const unsigned char* __restrict__ vt,
                                              double* __restrict__ acc) {
  __shared__ float s_red[4][3];
  int blk = blockIdx.x;            // BB*128
  int b   = blk >> 7;
  int y0  = (blk & 127) * 4;
  int tid = threadIdx.x;
  int wv = tid >> 6, lane = tid & 63;
  int y  = y0 + wv;
  int x0 = lane * 8;

  const float* prow = pred + (size_t)b * HWQ + (size_t)y * WW + x0;
  float4 pA = *(const float4*)prow;
  float4 pB = *(const float4*)(prow + 4);

  const unsigned char* vrow = vt + (size_t)b * HWQ + (size_t)y * WW;
  uint2 w0 = ld8(vrow, x0 - 16);
  uint2 w1 = ld8(vrow, x0 - 8);
  uint2 w2 = *(const uint2*)(vrow + x0);      // always in-bounds
  uint2 w3 = ld8(vrow, x0 + 8);
  uint2 w4 = ld8(vrow, x0 + 16);

  // packed-byte vertical sobel composites from embedded m/z/q bits
  unsigned zl = (w2.x >> 5) & 0x01010101u, zh = (w2.y >> 5) & 0x01010101u;
  unsigned ml = (w2.x >> 6) & 0x01010101u, mh = (w2.y >> 6) & 0x01010101u;
  unsigned ql = (w2.x >> 7) & 0x01010101u, qh = (w2.y >> 7) & 0x01010101u;
  unsigned uLo = ml + ql + 2u * zl;           // u = m+2z+q, bytes 0..4
  unsigned uHi = mh + qh + 2u * zh;
  unsigned vLo = (ql + 0x01010101u) - ml;     // v+1, bytes 0..2 (no borrow)
  unsigned vHi = (qh + 0x01010101u) - mh;
  // halos: col x0-1 = byte7 of w1 (0-masked at edge), col x0+8 = byte0 of w3
  int zm1 = (int)((w1.y >> 29) & 1u), mm1 = (int)((w1.y >> 30) & 1u), qm1 = (int)(w1.y >> 31);
  int zp8 = (int)((w3.x >> 5) & 1u),  mp8 = (int)((w3.x >> 6) & 1u),  qp8 = (int)((w3.x >> 7) & 1u);
  int uM1 = mm1 + 2*zm1 + qm1, vM1 = qm1 - mm1 + 1;
  int uP8 = mp8 + 2*zp8 + qp8, vP8 = qp8 - mp8 + 1;

#define UB(W,J) ((int)(((W) >> (8*(J))) & 7u))
#define VB(W,J) ((int)(((W) >> (8*(J))) & 3u))
  int u0=UB(uLo,0), u1=UB(uLo,1), u2c=UB(uLo,2), u3=UB(uLo,3);
  int u4=UB(uHi,0), u5=UB(uHi,1), u6=UB(uHi,2), u7=UB(uHi,3);
  int v0=VB(vLo,0), v1=VB(vLo,1), v2c=VB(vLo,2), v3=VB(vLo,3);
  int v4=VB(vHi,0), v5=VB(vHi,1), v6=VB(vHi,2), v7=VB(vHi,3);
  int t0=(int)((w2.x>>5)&1u),  t1=(int)((w2.x>>13)&1u), t2=(int)((w2.x>>21)&1u), t3=(int)((w2.x>>29)&1u);
  int t4=(int)((w2.y>>5)&1u),  t5=(int)((w2.y>>13)&1u), t6=(int)((w2.y>>21)&1u), t7=(int)((w2.y>>29)&1u);

  // initial 31-window vsum for col x0: bytes 1..31 (5-bit fields, packed adds, max 248)
  unsigned p0 = (w0.x & 0x1F1F1F1Fu) + (w0.y & 0x1F1F1F1Fu)
              + (w1.x & 0x1F1F1F1Fu) + (w1.y & 0x1F1F1F1Fu)
              + (w2.x & 0x1F1F1F1Fu) + (w2.y & 0x1F1F1F1Fu)
              + (w3.x & 0x1F1F1F1Fu) + (w3.y & 0x1F1F1F1Fu);
  int sw = sum4b(p0) - (int)(w0.x & 0x1Fu);

  float a_c = 0.f, a_pt = 0.f, a_p = 0.f;
  STEP(0, uM1, u1,  vM1, v0,  v1,  t0, pA.x);
  STEP(1, u0,  u2c, v0,  v1,  v2c, t1, pA.y);
  STEP(2, u1,  u3,  v1,  v2c, v3,  t2, pA.z);
  STEP(3, u2c, u4,  v2c, v3,  v4,  t3, pA.w);
  STEP(4, u3,  u5,  v3,  v4,  v5,  t4, pB.x);
  STEP(5, u4,  u6,  v4,  v5,  v6,  t5, pB.y);
  STEP(6, u5,  u7,  v5,  v6,  v7,  t6, pB.z);
  STEP(7, u6,  uP8, v6,  v7,  vP8, t7, pB.w);

  a_c = wredf(a_c); a_pt = wredf(a_pt); a_p = wredf(a_p);
  if (lane == 0) { s_red[wv][0] = a_c; s_red[wv][1] = a_pt; s_red[wv][2] = a_p; }
  __syncthreads();
  if (tid == 0) {
    float rc = 0, rpt = 0, rp = 0;
    for (int w = 0; w < 4; ++w) { rc += s_red[w][0]; rpt += s_red[w][1]; rp += s_red[w][2]; }
    atomicAdd(&acc[blk & 63],     (double)rc);
    atomicAdd(&acc[64 + 8*b + 0], (double)rpt);
    atomicAdd(&acc[64 + 8*b + 1], (double)rp);
  }
}

__global__ void k_final(const double* __restrict__ acc, const double* __restrict__ tpart,
                        float* __restrict__ out) {
  int t = threadIdx.x;  // 64 threads = 1 wave; t = image index
  double cs = acc[t];
  double TP = acc[64 + 8*t], Ps = acc[64 + 8*t + 1];
  double Ts = 0.0;
  for (int j = 0; j < 32; ++j) Ts += tpart[t * 32 + j];   // 32 k_bits blocks per image
  double FP = Ps - TP, FN = Ts - TP;
  double tv = (TP + 1e-6) / (TP + 0.3 * FP + 0.7 * FN + 1e-6);
  double om = 1.0 - tv;
  if (om < 0.0) om = 0.0;
  double term = pow(om, 1.0 / 1.33);
#pragma unroll
  for (int o = 32; o > 0; o >>= 1) {
    cs   += __shfl_down(cs, o, 64);
    term += __shfl_down(term, o, 64);
  }
  if (t == 0) {
    double ftl = term / 64.0;
    double n = (double)NTOT;
    out[0] = (float)(ftl - 0.6931471805599453 * cs / n);  // bce = -ln2 * log2(q)
  }
}

extern "C" void kernel_launch(void* const* d_in, const int* in_sizes, int n_in,
                              void* d_out, int out_size, void* d_ws, size_t ws_size,
                              hipStream_t stream) {
  (void)in_sizes; (void)n_in; (void)out_size; (void)ws_size;
  const float* pred = (const float*)d_in[0];
  const float* tgt  = (const float*)d_in[1];
  unsigned* bits = (unsigned*)d_ws;
  unsigned char* vtb = (unsigned char*)d_ws + BITS_BYTES;
  double* acc = (double*)((char*)d_ws + BITS_BYTES + NTOT);
  double* tpart = acc + ACC_MAIN_DOUBLES;

  k_bits<<<(int)(NTOT / 8192), 256, 0, stream>>>(tgt, bits, acc, tpart);
  k_vcol<<<1024, 256, 0, stream>>>((const unsigned char*)bits, vtb);
  k_main<<<BB * 128, 256, 0, stream>>>(pred, vtb, acc);
  k_final<<<1, 64, 0, stream>>>(acc, tpart, (float*)d_out);
}

// Round 13
// 58.872 us; speedup vs baseline: 1.1901x; 1.0561x over previous
//
#include <hip/hip_runtime.h>
#include <math.h>

#define BB 64
#define HH 512
#define WW 512
#define HWQ (HH*WW)
#define NTOT ((size_t)BB*HWQ)

// ws layout:
//  [0, 2MB)   : target bitmask, 1 bit/px (byte bc of row r covers cols 8bc..8bc+7)
//  then doubles:
//   [0..63]      a_c slots (k_fused atomics; zeroed by k_bits block 0)
//   [64+8b+0,1]  TP_b, sumP_b (k_fused atomics; zeroed by k_bits block 0)
//   [576+blk]    k_bits per-block t-count partials (plain stores)
#define BITS_BYTES (NTOT / 8)
#define ACC_MAIN_DOUBLES 576

// target f32 -> bitmask + per-block t-count. 2048 blocks, 32 px/thread. (proven R10)
__global__ __launch_bounds__(256) void k_bits(const float* __restrict__ tgt,
                                              unsigned* __restrict__ bits,
                                              double* __restrict__ accz,
                                              double* __restrict__ tpart) {
  if (blockIdx.x == 0) {
    for (int i = threadIdx.x; i < ACC_MAIN_DOUBLES; i += 256) accz[i] = 0.0;
  }
  size_t base = (size_t)blockIdx.x * 8192 + (size_t)threadIdx.x * 32;
  const float* p = tgt + base;
  unsigned wrd = 0u;
#pragma unroll
  for (int k = 0; k < 8; ++k) {
    const float4 t = *(const float4*)(p + 4 * k);
    wrd |= ((__float_as_uint(t.x) >> 29) & 1u) << (4 * k + 0);   // 1.0f -> 1, 0.0f -> 0
    wrd |= ((__float_as_uint(t.y) >> 29) & 1u) << (4 * k + 1);
    wrd |= ((__float_as_uint(t.z) >> 29) & 1u) << (4 * k + 2);
    wrd |= ((__float_as_uint(t.w) >> 29) & 1u) << (4 * k + 3);
  }
  bits[(size_t)blockIdx.x * 256 + threadIdx.x] = wrd;
  int cnt = __popc(wrd);
#pragma unroll
  for (int o = 32; o > 0; o >>= 1) cnt += __shfl_down(cnt, o, 64);
  __shared__ int s_t[4];
  int wv = threadIdx.x >> 6, lane = threadIdx.x & 63;
  if (lane == 0) s_t[wv] = cnt;
  __syncthreads();
  if (threadIdx.x == 0)
    tpart[blockIdx.x] = (double)(s_t[0] + s_t[1] + s_t[2] + s_t[3]);
}

__device__ inline float wredf(float v) {
#pragma unroll
  for (int o = 32; o > 0; o >>= 1) v += __shfl_down(v, o, 64);
  return v;
}

// nibble -> byte-lane spread (bit j of nibble -> byte j)
#define SPL(B) ((((B) & 0xFu) * 0x00204081u) & 0x01010101u)
#define SPH(B) ((((B) >> 4)   * 0x00204081u) & 0x01010101u)

__device__ inline int sum4b(unsigned x) {     // sum of the 4 bytes
  unsigned t = (x & 0x00FF00FFu) + ((x >> 8) & 0x00FF00FFu);
  return (int)((t + (t >> 16)) & 0xFFFFu);
}

// window byte I (0..39) <-> col x0-16+I ; I compile-time -> folds to one bfe
#define VTW(I) ((I) < 8  ? (((I)&7) < 4 ? w0.x : w0.y) : \
                (I) < 16 ? (((I)&7) < 4 ? w1.x : w1.y) : \
                (I) < 24 ? (((I)&7) < 4 ? w2.x : w2.y) : \
                (I) < 32 ? (((I)&7) < 4 ? w3.x : w3.y) : \
                           (((I)&7) < 4 ? w4.x : w4.y))
#define BGET5(I) ((int)((VTW(I) >> (((I)&3)*8)) & 31u))   // 5-bit vsum field

// one output column (identical math to R8/R12, which passed)
#define STEP(C, UM, UP, VM, VC, VP, TCI, PV) do {                     \
    int gx = (UP) - (UM);                                             \
    int gy = (VM) + 2*(VC) + (VP) - 4;                                \
    float tb = __builtin_amdgcn_sqrtf((float)(gx*gx + gy*gy) + 1e-12f); \
    float qq = (TCI) ? (PV) : 1.f - (PV);                             \
    float lg = __log2f(qq);                                           \
    int   di = (TCI) ? (961 - sw) : sw;                               \
    float wgt = fmaf(5.f, tb, fmaf(1.5608741e-3f, (float)di, 0.8f));  \
    a_c = fmaf(wgt, lg, a_c);                                         \
    a_pt += (TCI) ? (PV) : 0.f;                                       \
    a_p  += (PV);                                                     \
    sw += BGET5((C)+32) - BGET5((C)+1);                               \
  } while (0)

#define UB(W,J) ((int)(((W) >> (8*(J))) & 7u))            // u byte (0..4)
#define VB(W,J) ((int)(((W) >> (8*(J))) & 3u))            // v+1 byte (0..2)

// fully fused kernel: block = 16 rows of one image; lane = byte-col bc (8 cols);
// thread covers 4 rows. Vertical 31-row box sums as rolling SWAR byte counters
// over the L2-resident bitmask; neighbor vt-windows assembled via __shfl;
// horizontal pass is the R8-proven STEP block. No LDS staging, no intermediate.
__global__ __launch_bounds__(256) void k_fused(const float* __restrict__ pred,
                                               const unsigned char* __restrict__ bitsb,
                                               double* __restrict__ acc) {
  __shared__ float s_red[4][3];
  int blk  = blockIdx.x;           // 2048 = 64 img x 32 bands
  int b    = blk >> 5;
  int band = blk & 31;
  int tid  = threadIdx.x;
  int wv   = tid >> 6, lane = tid & 63;
  int ys   = band * 16 + wv * 4;
  int x0   = lane * 8;

  const unsigned char* bimg = bitsb + (size_t)b * (HWQ / 8);
  const float* pimg = pred + (size_t)b * HWQ;

  // vertical init: box window rows ys-15 .. ys+15 (row bounds wave-uniform)
  unsigned cLo = 0u, cHi = 0u;
  for (int r = ys - 15; r <= ys + 15; ++r) {
    unsigned v = ((unsigned)r < HH) ? (unsigned)bimg[r * 64 + lane] : 0u;
    cLo += SPL(v); cHi += SPH(v);
  }
  unsigned bm = (ys >= 1) ? (unsigned)bimg[(ys - 1) * 64 + lane] : 0u;
  unsigned bz = (unsigned)bimg[ys * 64 + lane];

  float a_c = 0.f, a_pt = 0.f, a_p = 0.f;
#pragma unroll
  for (int j = 0; j < 4; ++j) {
    int y = ys + j;
    unsigned bq = ((unsigned)(y + 1) < HH) ? (unsigned)bimg[(y + 1) * 64 + lane] : 0u;
    // own vt8 words (vsum | t<<5 | t(y-1)<<6 | t(y+1)<<7 per byte)
    unsigned w2x = cLo | (SPL(bz) << 5) | (SPL(bm) << 6) | (SPL(bq) << 7);
    unsigned w2y = cHi | (SPH(bz) << 5) | (SPH(bm) << 6) | (SPH(bq) << 7);
    // neighbor windows via shfl (edge lanes masked = image-edge zero pad)
    unsigned w1x = __shfl_up(w2x, 1, 64),  w1y = __shfl_up(w2y, 1, 64);
    unsigned w0x = __shfl_up(w2x, 2, 64),  w0y = __shfl_up(w2y, 2, 64);
    unsigned w3x = __shfl_down(w2x, 1, 64), w3y = __shfl_down(w2y, 1, 64);
    unsigned w4x = __shfl_down(w2x, 2, 64), w4y = __shfl_down(w2y, 2, 64);
    if (lane < 1)  { w1x = 0u; w1y = 0u; }
    if (lane < 2)  { w0x = 0u; w0y = 0u; }
    if (lane > 62) { w3x = 0u; w3y = 0u; }
    if (lane > 61) { w4x = 0u; w4y = 0u; }
    uint2 w0 = make_uint2(w0x, w0y), w1 = make_uint2(w1x, w1y), w2 = make_uint2(w2x, w2y),
          w3 = make_uint2(w3x, w3y), w4 = make_uint2(w4x, w4y);

    // ---- R8-proven horizontal pass ----
    const float* prow = pimg + (size_t)y * WW + x0;
    float4 pA = *(const float4*)prow;
    float4 pB = *(const float4*)(prow + 4);

    unsigned zl = (w2.x >> 5) & 0x01010101u, zh = (w2.y >> 5) & 0x01010101u;
    unsigned ml = (w2.x >> 6) & 0x01010101u, mh = (w2.y >> 6) & 0x01010101u;
    unsigned ql = (w2.x >> 7) & 0x01010101u, qh = (w2.y >> 7) & 0x01010101u;
    unsigned uLo = ml + ql + 2u * zl;           // u = m+2z+q, bytes 0..4
    unsigned uHi = mh + qh + 2u * zh;
    unsigned vLo = (ql + 0x01010101u) - ml;     // v+1, bytes 0..2 (no borrow)
    unsigned vHi = (qh + 0x01010101u) - mh;
    int zm1 = (int)((w1.y >> 29) & 1u), mm1 = (int)((w1.y >> 30) & 1u), qm1 = (int)(w1.y >> 31);
    int zp8 = (int)((w3.x >> 5) & 1u),  mp8 = (int)((w3.x >> 6) & 1u),  qp8 = (int)((w3.x >> 7) & 1u);
    int uM1 = mm1 + 2*zm1 + qm1, vM1 = qm1 - mm1 + 1;
    int uP8 = mp8 + 2*zp8 + qp8, vP8 = qp8 - mp8 + 1;

    int u0=UB(uLo,0), u1=UB(uLo,1), u2c=UB(uLo,2), u3=UB(uLo,3);
    int u4=UB(uHi,0), u5=UB(uHi,1), u6=UB(uHi,2), u7=UB(uHi,3);
    int v0=VB(vLo,0), v1=VB(vLo,1), v2c=VB(vLo,2), v3=VB(vLo,3);
    int v4=VB(vHi,0), v5=VB(vHi,1), v6=VB(vHi,2), v7=VB(vHi,3);
    int t0=(int)((w2.x>>5)&1u),  t1=(int)((w2.x>>13)&1u), t2=(int)((w2.x>>21)&1u), t3=(int)((w2.x>>29)&1u);
    int t4=(int)((w2.y>>5)&1u),  t5=(int)((w2.y>>13)&1u), t6=(int)((w2.y>>21)&1u), t7=(int)((w2.y>>29)&1u);

    unsigned p0 = (w0.x & 0x1F1F1F1Fu) + (w0.y & 0x1F1F1F1Fu)
                + (w1.x & 0x1F1F1F1Fu) + (w1.y & 0x1F1F1F1Fu)
                + (w2.x & 0x1F1F1F1Fu) + (w2.y & 0x1F1F1F1Fu)
                + (w3.x & 0x1F1F1F1Fu) + (w3.y & 0x1F1F1F1Fu);
    int sw = sum4b(p0) - (int)(w0.x & 0x1Fu);

    STEP(0, uM1, u1,  vM1, v0,  v1,  t0, pA.x);
    STEP(1, u0,  u2c, v0,  v1,  v2c, t1, pA.y);
    STEP(2, u1,  u3,  v1,  v2c, v3,  t2, pA.z);
    STEP(3, u2c, u4,  v2c, v3,  v4,  t3, pA.w);
    STEP(4, u3,  u5,  v3,  v4,  v5,  t4, pB.x);
    STEP(5, u4,  u6,  v4,  v5,  v6,  t5, pB.y);
    STEP(6, u5,  u7,  v5,  v6,  v7,  t6, pB.z);
    STEP(7, u6,  uP8, v6,  v7,  vP8, t7, pB.w);
    // ---- end horizontal pass ----

    // rolling vertical update for next row
    unsigned ba = ((unsigned)(y + 16) < HH) ? (unsigned)bimg[(y + 16) * 64 + lane] : 0u;
    unsigned bs = ((unsigned)(y - 15) < HH) ? (unsigned)bimg[(y - 15) * 64 + lane] : 0u;
    cLo += SPL(ba) - SPL(bs);
    cHi += SPH(ba) - SPH(bs);
    bm = bz; bz = bq;
  }

  a_c = wredf(a_c); a_pt = wredf(a_pt); a_p = wredf(a_p);
  if (lane == 0) { s_red[wv][0] = a_c; s_red[wv][1] = a_pt; s_red[wv][2] = a_p; }
  __syncthreads();
  if (tid == 0) {
    float rc = 0, rpt = 0, rp = 0;
    for (int w = 0; w < 4; ++w) { rc += s_red[w][0]; rpt += s_red[w][1]; rp += s_red[w][2]; }
    atomicAdd(&acc[blk & 63],     (double)rc);
    atomicAdd(&acc[64 + 8*b + 0], (double)rpt);
    atomicAdd(&acc[64 + 8*b + 1], (double)rp);
  }
}

__global__ void k_final(const double* __restrict__ acc, const double* __restrict__ tpart,
                        float* __restrict__ out) {
  int t = threadIdx.x;  // 64 threads = 1 wave; t = image index
  double cs = acc[t];
  double TP = acc[64 + 8*t], Ps = acc[64 + 8*t + 1];
  double Ts = 0.0;
  for (int j = 0; j < 32; ++j) Ts += tpart[t * 32 + j];   // 32 k_bits blocks per image
  double FP = Ps - TP, FN = Ts - TP;
  double tv = (TP + 1e-6) / (TP + 0.3 * FP + 0.7 * FN + 1e-6);
  double om = 1.0 - tv;
  if (om < 0.0) om = 0.0;
  double term = pow(om, 1.0 / 1.33);
#pragma unroll
  for (int o = 32; o > 0; o >>= 1) {
    cs   += __shfl_down(cs, o, 64);
    term += __shfl_down(term, o, 64);
  }
  if (t == 0) {
    double ftl = term / 64.0;
    double n = (double)NTOT;
    out[0] = (float)(ftl - 0.6931471805599453 * cs / n);  // bce = -ln2 * log2(q)
  }
}

extern "C" void kernel_launch(void* const* d_in, const int* in_sizes, int n_in,
                              void* d_out, int out_size, void* d_ws, size_t ws_size,
                              hipStream_t stream) {
  (void)in_sizes; (void)n_in; (void)out_size; (void)ws_size;
  const float* pred = (const float*)d_in[0];
  const float* tgt  = (const float*)d_in[1];
  unsigned* bits = (unsigned*)d_ws;
  double* acc = (double*)((char*)d_ws + BITS_BYTES);
  double* tpart = acc + ACC_MAIN_DOUBLES;

  k_bits<<<(int)(NTOT / 8192), 256, 0, stream>>>(tgt, bits, acc, tpart);
  k_fused<<<BB * 32, 256, 0, stream>>>(pred, (const unsigned char*)bits, acc);
  k_final<<<1, 64, 0, stream>>>(acc, tpart, (float*)d_out);
}

// Round 14
// 56.184 us; speedup vs baseline: 1.2471x; 1.0479x over previous
//
#include <hip/hip_runtime.h>
#include <math.h>

#define BB 64
#define HH 512
#define WW 512
#define HWQ (HH*WW)
#define NTOT ((size_t)BB*HWQ)

// ws layout:
//  [0, 2MB)        : TRANSPOSED bitmask: byte for (b, bytecol bc, row r) at
//                    bitsT[((b*32 + (r>>4))*64 + bc)*16 + (r&15)]
//  [2MB, 18MB)     : vt8 per px = vsum(0..31) | t<<5 | t(y-1)<<6 | t(y+1)<<7
//  then doubles:
//   [0..63]      a_c slots (k_main atomics; zeroed by k_bitsT block 0)
//   [64+8b+0,1]  TP_b, sumP_b (k_main atomics; zeroed by k_bitsT block 0)
//   [576+blk]    k_bitsT per-block t-count partials (plain stores)
#define BITS_BYTES (NTOT / 8)
#define ACC_MAIN_DOUBLES 576

#define FU(X) (__float_as_uint(X))

// target f32 -> transposed bitmask + per-block t-count. 1024 blocks.
// wave: lane = bytecol, all lanes same rows -> 2KB coalesced reads per row.
__global__ __launch_bounds__(256) void k_bitsT(const float* __restrict__ tgt,
                                               unsigned char* __restrict__ bitsT,
                                               double* __restrict__ accz,
                                               double* __restrict__ tpart) {
  if (blockIdx.x == 0) {
    for (int i = threadIdx.x; i < ACC_MAIN_DOUBLES; i += 256) accz[i] = 0.0;
  }
  int tid  = threadIdx.x;
  int bc   = tid & 63;
  int unit = blockIdx.x * 4 + (tid >> 6);   // 4096 units = 64 img x 64 rowgroups(8)
  int b    = unit >> 6;
  int rg   = unit & 63;
  int r0   = rg * 8;
  const float* timg = tgt + (size_t)b * HWQ;
  unsigned wlo = 0u, whi = 0u;
#pragma unroll
  for (int j = 0; j < 8; ++j) {
    const float* rp = timg + (size_t)(r0 + j) * WW + bc * 8;
    float4 a = *(const float4*)rp;
    float4 c = *(const float4*)(rp + 4);
    unsigned by = ((FU(a.x) >> 29) & 1u)        | (((FU(a.y) >> 29) & 1u) << 1)
                | (((FU(a.z) >> 29) & 1u) << 2) | (((FU(a.w) >> 29) & 1u) << 3)
                | (((FU(c.x) >> 29) & 1u) << 4) | (((FU(c.y) >> 29) & 1u) << 5)
                | (((FU(c.z) >> 29) & 1u) << 6) | (((FU(c.w) >> 29) & 1u) << 7);
    if (j < 4) wlo |= by << (8 * j); else whi |= by << (8 * (j - 4));
  }
  int rb = r0 >> 4, off = r0 & 15;
  *(uint2*)(bitsT + (((size_t)(b * 32 + rb) * 64 + bc) << 4) + off) = make_uint2(wlo, whi);

  int cnt = __popc(wlo) + __popc(whi);
#pragma unroll
  for (int o = 32; o > 0; o >>= 1) cnt += __shfl_down(cnt, o, 64);
  __shared__ int s_t[4];
  int wv = tid >> 6, lane = tid & 63;
  if (lane == 0) s_t[wv] = cnt;
  __syncthreads();
  if (tid == 0) tpart[blockIdx.x] = (double)(s_t[0] + s_t[1] + s_t[2] + s_t[3]);
}

// nibble -> byte-lane spread (bit j of nibble -> byte j)
#define SPL(B) ((((B) & 0xFu) * 0x00204081u) & 0x01010101u)
#define SPH(B) ((((B) >> 4)   * 0x00204081u) & 0x01010101u)

// byte K (0..47) of the 3-block register window B0,B1,B2 (K compile-time)
#define W48(K) ((K)<16 ? (((K)&15)<8 ? (((K)&15)<4?B0.x:B0.y) : (((K)&15)<12?B0.z:B0.w)) \
              : (K)<32 ? (((K)&15)<8 ? (((K)&15)<4?B1.x:B1.y) : (((K)&15)<12?B1.z:B1.w)) \
                       : (((K)&15)<8 ? (((K)&15)<4?B2.x:B2.y) : (((K)&15)<12?B2.z:B2.w)))
#define BYTE48(K) ((W48(K) >> (((K)&3)*8)) & 0xFFu)

// rows: byte K <-> row 16*s2 - 16 + K ; row ys+j <-> K = j + 16 + E
template<int E>
__device__ __forceinline__ void vcol_body(uint4 B0, uint4 B1, uint4 B2,
                                          unsigned char* __restrict__ vout) {
  unsigned cLo = 0u, cHi = 0u;
#pragma unroll
  for (int j = -15; j <= 15; ++j) {
    unsigned by = BYTE48(j + 16 + E);
    cLo += SPL(by); cHi += SPH(by);
  }
  unsigned bm = BYTE48(15 + E);   // row ys-1 (OOB rows auto-zero via zeroed blocks)
  unsigned bz = BYTE48(16 + E);   // row ys
#pragma unroll
  for (int j = 0; j < 8; ++j) {
    unsigned bq = BYTE48(17 + E + j);   // row ys+j+1
    unsigned outLo = cLo | (SPL(bz) << 5) | (SPL(bm) << 6) | (SPL(bq) << 7);
    unsigned outHi = cHi | (SPH(bz) << 5) | (SPH(bm) << 6) | (SPH(bq) << 7);
    *(uint2*)(vout + (size_t)j * WW) = make_uint2(outLo, outHi);
    unsigned ba = BYTE48(32 + E + j);   // row ys+j+16
    unsigned bs = BYTE48(1 + E + j);    // row ys+j-15
    cLo += SPL(ba) - SPL(bs);
    cHi += SPH(ba) - SPH(bs);
    bm = bz; bz = bq;
  }
}

// transposed bits -> vt8. Thread = bytecol x 8 rows; 3 coalesced uint4 loads
// put the whole vertical window in registers (no load in the scan chain).
__global__ __launch_bounds__(256) void k_vcolT(const unsigned char* __restrict__ bitsT,
                                               unsigned char* __restrict__ vt) {
  int tid  = threadIdx.x;
  int bc   = tid & 63;
  int unit = blockIdx.x * 4 + (tid >> 6);   // 4096 units = 64 img x 64 segs(8)
  int b    = unit >> 6;
  int seg  = unit & 63;
  int ys   = seg * 8;
  int s2   = seg >> 1;

  uint4 B0 = make_uint4(0u,0u,0u,0u), B2 = make_uint4(0u,0u,0u,0u);
  if (s2 >= 1)  B0 = *(const uint4*)(bitsT + (((size_t)(b * 32 + s2 - 1) * 64 + bc) << 4));
  uint4 B1      = *(const uint4*)(bitsT + (((size_t)(b * 32 + s2)     * 64 + bc) << 4));
  if (s2 <= 30) B2 = *(const uint4*)(bitsT + (((size_t)(b * 32 + s2 + 1) * 64 + bc) << 4));

  unsigned char* vout = vt + (size_t)b * HWQ + (size_t)ys * WW + bc * 8;
  if ((seg & 1) == 0) vcol_body<0>(B0, B1, B2, vout);
  else                vcol_body<8>(B0, B1, B2, vout);
}

__device__ inline float wredf(float v) {
#pragma unroll
  for (int o = 32; o > 0; o >>= 1) v += __shfl_down(v, o, 64);
  return v;
}

// 8-byte-granular masked load (col boundaries are 8B-aligned)
__device__ inline uint2 ld8(const unsigned char* __restrict__ row, int off) {
  bool ok = (off >= 0) & (off <= WW - 8);
  int oc = ok ? off : 0;
  uint2 v = *(const uint2*)(row + oc);
  if (!ok) { v.x = 0u; v.y = 0u; }
  return v;
}

__device__ inline int sum4b(unsigned x) {     // sum of the 4 bytes
  unsigned t = (x & 0x00FF00FFu) + ((x >> 8) & 0x00FF00FFu);
  return (int)((t + (t >> 16)) & 0xFFFFu);
}

// window byte I (0..39) <-> col x0-16+I ; I compile-time -> folds to one bfe
#define VTW(I) ((I) < 8  ? (((I)&7) < 4 ? w0.x : w0.y) : \
                (I) < 16 ? (((I)&7) < 4 ? w1.x : w1.y) : \
                (I) < 24 ? (((I)&7) < 4 ? w2.x : w2.y) : \
                (I) < 32 ? (((I)&7) < 4 ? w3.x : w3.y) : \
                           (((I)&7) < 4 ? w4.x : w4.y))
#define BGET5(I) ((int)((VTW(I) >> (((I)&3)*8)) & 31u))   // 5-bit vsum field

// one output column (identical math to R8/R12, which passed)
#define STEP(C, UM, UP, VM, VC, VP, TCI, PV) do {                     \
    int gx = (UP) - (UM);                                             \
    int gy = (VM) + 2*(VC) + (VP) - 4;                                \
    float tb = __builtin_amdgcn_sqrtf((float)(gx*gx + gy*gy) + 1e-12f); \
    float qq = (TCI) ? (PV) : 1.f - (PV);                             \
    float lg = __log2f(qq);                                           \
    int   di = (TCI) ? (961 - sw) : sw;                               \
    float wgt = fmaf(5.f, tb, fmaf(1.5608741e-3f, (float)di, 0.8f));  \
    a_c = fmaf(wgt, lg, a_c);                                         \
    a_pt += (TCI) ? (PV) : 0.f;                                       \
    a_p  += (PV);                                                     \
    sw += BGET5((C)+32) - BGET5((C)+1);                               \
  } while (0)

#define UB(W,J) ((int)(((W) >> (8*(J))) & 7u))            // u byte (0..4)
#define VB(W,J) ((int)(((W) >> (8*(J))) & 3u))            // v+1 byte (0..2)

// main fused kernel (R12-verbatim, proven): reads ONLY pred f32 + vt8 windows.
__global__ __launch_bounds__(256) void k_main(const float* __restrict__ pred,
                                              const unsigned char* __restrict__ vt,
                                              double* __restrict__ acc) {
  __shared__ float s_red[4][3];
  int blk = blockIdx.x;            // BB*128
  int b   = blk >> 7;
  int y0  = (blk & 127) * 4;
  int tid = threadIdx.x;
  int wv = tid >> 6, lane = tid & 63;
  int y  = y0 + wv;
  int x0 = lane * 8;

  const float* prow = pred + (size_t)b * HWQ + (size_t)y * WW + x0;
  float4 pA = *(const float4*)prow;
  float4 pB = *(const float4*)(prow + 4);

  const unsigned char* vrow = vt + (size_t)b * HWQ + (size_t)y * WW;
  uint2 w0 = ld8(vrow, x0 - 16);
  uint2 w1 = ld8(vrow, x0 - 8);
  uint2 w2 = *(const uint2*)(vrow + x0);      // always in-bounds
  uint2 w3 = ld8(vrow, x0 + 8);
  uint2 w4 = ld8(vrow, x0 + 16);

  // packed-byte vertical sobel composites from embedded m/z/q bits
  unsigned zl = (w2.x >> 5) & 0x01010101u, zh = (w2.y >> 5) & 0x01010101u;
  unsigned ml = (w2.x >> 6) & 0x01010101u, mh = (w2.y >> 6) & 0x01010101u;
  unsigned ql = (w2.x >> 7) & 0x01010101u, qh = (w2.y >> 7) & 0x01010101u;
  unsigned uLo = ml + ql + 2u * zl;           // u = m+2z+q, bytes 0..4
  unsigned uHi = mh + qh + 2u * zh;
  unsigned vLo = (ql + 0x01010101u) - ml;     // v+1, bytes 0..2 (no borrow)
  unsigned vHi = (qh + 0x01010101u) - mh;
  // halos: col x0-1 = byte7 of w1 (0-masked at edge), col x0+8 = byte0 of w3
  int zm1 = (int)((w1.y >> 29) & 1u), mm1 = (int)((w1.y >> 30) & 1u), qm1 = (int)(w1.y >> 31);
  int zp8 = (int)((w3.x >> 5) & 1u),  mp8 = (int)((w3.x >> 6) & 1u),  qp8 = (int)((w3.x >> 7) & 1u);
  int uM1 = mm1 + 2*zm1 + qm1, vM1 = qm1 - mm1 + 1;
  int uP8 = mp8 + 2*zp8 + qp8, vP8 = qp8 - mp8 + 1;

  int u0=UB(uLo,0), u1=UB(uLo,1), u2c=UB(uLo,2), u3=UB(uLo,3);
  int u4=UB(uHi,0), u5=UB(uHi,1), u6=UB(uHi,2), u7=UB(uHi,3);
  int v0=VB(vLo,0), v1=VB(vLo,1), v2c=VB(vLo,2), v3=VB(vLo,3);
  int v4=VB(vHi,0), v5=VB(vHi,1), v6=VB(vHi,2), v7=VB(vHi,3);
  int t0=(int)((w2.x>>5)&1u),  t1=(int)((w2.x>>13)&1u), t2=(int)((w2.x>>21)&1u), t3=(int)((w2.x>>29)&1u);
  int t4=(int)((w2.y>>5)&1u),  t5=(int)((w2.y>>13)&1u), t6=(int)((w2.y>>21)&1u), t7=(int)((w2.y>>29)&1u);

  // initial 31-window vsum for col x0: bytes 1..31 (5-bit fields, packed adds, max 248)
  unsigned p0 = (w0.x & 0x1F1F1F1Fu) + (w0.y & 0x1F1F1F1Fu)
              + (w1.x & 0x1F1F1F1Fu) + (w1.y & 0x1F1F1F1Fu)
              + (w2.x & 0x1F1F1F1Fu) + (w2.y & 0x1F1F1F1Fu)
              + (w3.x & 0x1F1F1F1Fu) + (w3.y & 0x1F1F1F1Fu);
  int sw = sum4b(p0) - (int)(w0.x & 0x1Fu);

  float a_c = 0.f, a_pt = 0.f, a_p = 0.f;
  STEP(0, uM1, u1,  vM1, v0,  v1,  t0, pA.x);
  STEP(1, u0,  u2c, v0,  v1,  v2c, t1, pA.y);
  STEP(2, u1,  u3,  v1,  v2c, v3,  t2, pA.z);
  STEP(3, u2c, u4,  v2c, v3,  v4,  t3, pA.w);
  STEP(4, u3,  u5,  v3,  v4,  v5,  t4, pB.x);
  STEP(5, u4,  u6,  v4,  v5,  v6,  t5, pB.y);
  STEP(6, u5,  u7,  v5,  v6,  v7,  t6, pB.z);
  STEP(7, u6,  uP8, v6,  v7,  vP8, t7, pB.w);

  a_c = wredf(a_c); a_pt = wredf(a_pt); a_p = wredf(a_p);
  if (lane == 0) { s_red[wv][0] = a_c; s_red[wv][1] = a_pt; s_red[wv][2] = a_p; }
  __syncthreads();
  if (tid == 0) {
    float rc = 0, rpt = 0, rp = 0;
    for (int w = 0; w < 4; ++w) { rc += s_red[w][0]; rpt += s_red[w][1]; rp += s_red[w][2]; }
    atomicAdd(&acc[blk & 63],     (double)rc);
    atomicAdd(&acc[64 + 8*b + 0], (double)rpt);
    atomicAdd(&acc[64 + 8*b + 1], (double)rp);
  }
}

__global__ void k_final(const double* __restrict__ acc, const double* __restrict__ tpart,
                        float* __restrict__ out) {
  int t = threadIdx.x;  // 64 threads = 1 wave; t = image index
  double cs = acc[t];
  double TP = acc[64 + 8*t], Ps = acc[64 + 8*t + 1];
  double Ts = 0.0;
  for (int j = 0; j < 16; ++j) Ts += tpart[t * 16 + j];   // 16 k_bitsT blocks per image
  double FP = Ps - TP, FN = Ts - TP;
  double tv = (TP + 1e-6) / (TP + 0.3 * FP + 0.7 * FN + 1e-6);
  double om = 1.0 - tv;
  if (om < 0.0) om = 0.0;
  double term = pow(om, 1.0 / 1.33);
#pragma unroll
  for (int o = 32; o > 0; o >>= 1) {
    cs   += __shfl_down(cs, o, 64);
    term += __shfl_down(term, o, 64);
  }
  if (t == 0) {
    double ftl = term / 64.0;
    double n = (double)NTOT;
    out[0] = (float)(ftl - 0.6931471805599453 * cs / n);  // bce = -ln2 * log2(q)
  }
}

extern "C" void kernel_launch(void* const* d_in, const int* in_sizes, int n_in,
                              void* d_out, int out_size, void* d_ws, size_t ws_size,
                              hipStream_t stream) {
  (void)in_sizes; (void)n_in; (void)out_size; (void)ws_size;
  const float* pred = (const float*)d_in[0];
  const float* tgt  = (const float*)d_in[1];
  unsigned char* bitsT = (unsigned char*)d_ws;
  unsigned char* vtb   = (unsigned char*)d_ws + BITS_BYTES;
  double* acc = (double*)((char*)d_ws + BITS_BYTES + NTOT);
  double* tpart = acc + ACC_MAIN_DOUBLES;

  k_bitsT<<<1024, 256, 0, stream>>>(tgt, bitsT, acc, tpart);
  k_vcolT<<<1024, 256, 0, stream>>>(bitsT, vtb);
  k_main<<<BB * 128, 256, 0, stream>>>(pred, vtb, acc);
  k_final<<<1, 64, 0, stream>>>(acc, tpart, (float*)d_out);
}

// Round 15
// 44.112 us; speedup vs baseline: 1.5883x; 1.2736x over previous
//
#include <hip/hip_runtime.h>
#include <math.h>

#define BB 64
#define HH 512
#define WW 512
#define HWQ (HH*WW)
#define NTOT ((size_t)BB*HWQ)

// ws layout:
//  [0, 2MB)   : TRANSPOSED bitmask: byte for (b, bytecol bc, row r) at
//               bitsT[((b*32 + (r>>4))*64 + bc)*16 + (r&15)]
//  then doubles:
//   [0..63]      a_c slots (k_fused atomics; zeroed by k_bitsT block 0)
//   [64+8b+0,1]  TP_b, sumP_b (k_fused atomics; zeroed by k_bitsT block 0)
//   [576+blk]    k_bitsT per-block t-count partials (plain stores)
#define BITS_BYTES (NTOT / 8)
#define ACC_MAIN_DOUBLES 576

#define FU(X) (__float_as_uint(X))

// target f32 -> transposed bitmask + per-block t-count. 1024 blocks. (R14 proven)
__global__ __launch_bounds__(256) void k_bitsT(const float* __restrict__ tgt,
                                               unsigned char* __restrict__ bitsT,
                                               double* __restrict__ accz,
                                               double* __restrict__ tpart) {
  if (blockIdx.x == 0) {
    for (int i = threadIdx.x; i < ACC_MAIN_DOUBLES; i += 256) accz[i] = 0.0;
  }
  int tid  = threadIdx.x;
  int bc   = tid & 63;
  int unit = blockIdx.x * 4 + (tid >> 6);   // 4096 units = 64 img x 64 rowgroups(8)
  int b    = unit >> 6;
  int rg   = unit & 63;
  int r0   = rg * 8;
  const float* timg = tgt + (size_t)b * HWQ;
  unsigned wlo = 0u, whi = 0u;
#pragma unroll
  for (int j = 0; j < 8; ++j) {
    const float* rp = timg + (size_t)(r0 + j) * WW + bc * 8;
    float4 a = *(const float4*)rp;
    float4 c = *(const float4*)(rp + 4);
    unsigned by = ((FU(a.x) >> 29) & 1u)        | (((FU(a.y) >> 29) & 1u) << 1)
                | (((FU(a.z) >> 29) & 1u) << 2) | (((FU(a.w) >> 29) & 1u) << 3)
                | (((FU(c.x) >> 29) & 1u) << 4) | (((FU(c.y) >> 29) & 1u) << 5)
                | (((FU(c.z) >> 29) & 1u) << 6) | (((FU(c.w) >> 29) & 1u) << 7);
    if (j < 4) wlo |= by << (8 * j); else whi |= by << (8 * (j - 4));
  }
  int rb = r0 >> 4, off = r0 & 15;
  *(uint2*)(bitsT + (((size_t)(b * 32 + rb) * 64 + bc) << 4) + off) = make_uint2(wlo, whi);

  int cnt = __popc(wlo) + __popc(whi);
#pragma unroll
  for (int o = 32; o > 0; o >>= 1) cnt += __shfl_down(cnt, o, 64);
  __shared__ int s_t[4];
  int wv = tid >> 6, lane = tid & 63;
  if (lane == 0) s_t[wv] = cnt;
  __syncthreads();
  if (tid == 0) tpart[blockIdx.x] = (double)(s_t[0] + s_t[1] + s_t[2] + s_t[3]);
}

// nibble -> byte-lane spread (bit j of nibble -> byte j)
#define SPL(B) ((((B) & 0xFu) * 0x00204081u) & 0x01010101u)
#define SPH(B) ((((B) >> 4)   * 0x00204081u) & 0x01010101u)

// byte K (0..47) of the 3-block register window B0,B1,B2 (K compile-time)
#define W48(K) ((K)<16 ? (((K)&15)<8 ? (((K)&15)<4?B0.x:B0.y) : (((K)&15)<12?B0.z:B0.w)) \
              : (K)<32 ? (((K)&15)<8 ? (((K)&15)<4?B1.x:B1.y) : (((K)&15)<12?B1.z:B1.w)) \
                       : (((K)&15)<8 ? (((K)&15)<4?B2.x:B2.y) : (((K)&15)<12?B2.z:B2.w)))
#define BYTE48(K) ((W48(K) >> (((K)&3)*8)) & 0xFFu)

__device__ inline float wredf(float v) {
#pragma unroll
  for (int o = 32; o > 0; o >>= 1) v += __shfl_down(v, o, 64);
  return v;
}

__device__ inline int sum4b(unsigned x) {     // sum of the 4 bytes
  unsigned t = (x & 0x00FF00FFu) + ((x >> 8) & 0x00FF00FFu);
  return (int)((t + (t >> 16)) & 0xFFFFu);
}

// window byte I (0..39) <-> col x0-16+I ; I compile-time -> folds to one bfe
#define VTW(I) ((I) < 8  ? (((I)&7) < 4 ? w0.x : w0.y) : \
                (I) < 16 ? (((I)&7) < 4 ? w1.x : w1.y) : \
                (I) < 24 ? (((I)&7) < 4 ? w2.x : w2.y) : \
                (I) < 32 ? (((I)&7) < 4 ? w3.x : w3.y) : \
                           (((I)&7) < 4 ? w4.x : w4.y))
#define BGET5(I) ((int)((VTW(I) >> (((I)&3)*8)) & 31u))   // 5-bit vsum field

// one output column (identical math to R8/R12, which passed)
#define STEP(C, UM, UP, VM, VC, VP, TCI, PV) do {                     \
    int gx = (UP) - (UM);                                             \
    int gy = (VM) + 2*(VC) + (VP) - 4;                                \
    float tb = __builtin_amdgcn_sqrtf((float)(gx*gx + gy*gy) + 1e-12f); \
    float qq = (TCI) ? (PV) : 1.f - (PV);                             \
    float lg = __log2f(qq);                                           \
    int   di = (TCI) ? (961 - sw) : sw;                               \
    float wgt = fmaf(5.f, tb, fmaf(1.5608741e-3f, (float)di, 0.8f));  \
    a_c = fmaf(wgt, lg, a_c);                                         \
    a_pt += (TCI) ? (PV) : 0.f;                                       \
    a_p  += (PV);                                                     \
    sw += BGET5((C)+32) - BGET5((C)+1);                               \
  } while (0)

#define UB(W,J) ((int)(((W) >> (8*(J))) & 7u))            // u byte (0..4)
#define VB(W,J) ((int)(((W) >> (8*(J))) & 3u))            // v+1 byte (0..2)

// fused body: vertical SWAR scan (register-resident bit window) + per-row
// horizontal pass (R12-proven). E in {0,8} selects the seg parity row base.
template<int E>
__device__ __forceinline__ void fused_rows(uint4 B0, uint4 B1, uint4 B2,
                                           const float* __restrict__ prow,
                                           int lane,
                                           float& a_c, float& a_pt, float& a_p) {
  unsigned cLo = 0u, cHi = 0u;
#pragma unroll
  for (int j = -15; j <= 15; ++j) {
    unsigned by = BYTE48(j + 16 + E);
    cLo += SPL(by); cHi += SPH(by);
  }
  unsigned bm = BYTE48(15 + E);   // row ys-1 (OOB rows auto-zero via zeroed blocks)
  unsigned bz = BYTE48(16 + E);   // row ys
#pragma unroll
  for (int j = 0; j < 8; ++j) {
    unsigned bq = BYTE48(17 + E + j);   // row ys+j+1
    unsigned w2x = cLo | (SPL(bz) << 5) | (SPL(bm) << 6) | (SPL(bq) << 7);
    unsigned w2y = cHi | (SPH(bz) << 5) | (SPH(bm) << 6) | (SPH(bq) << 7);
    // neighbor windows via shfl (edge lanes masked = image-edge zero pad; R13-proven)
    unsigned w1x = __shfl_up(w2x, 1, 64),  w1y = __shfl_up(w2y, 1, 64);
    unsigned w0x = __shfl_up(w2x, 2, 64),  w0y = __shfl_up(w2y, 2, 64);
    unsigned w3x = __shfl_down(w2x, 1, 64), w3y = __shfl_down(w2y, 1, 64);
    unsigned w4x = __shfl_down(w2x, 2, 64), w4y = __shfl_down(w2y, 2, 64);
    if (lane < 1)  { w1x = 0u; w1y = 0u; }
    if (lane < 2)  { w0x = 0u; w0y = 0u; }
    if (lane > 62) { w3x = 0u; w3y = 0u; }
    if (lane > 61) { w4x = 0u; w4y = 0u; }
    uint2 w0 = make_uint2(w0x, w0y), w1 = make_uint2(w1x, w1y), w2 = make_uint2(w2x, w2y),
          w3 = make_uint2(w3x, w3y), w4 = make_uint2(w4x, w4y);

    float4 pA = *(const float4*)prow;
    float4 pB = *(const float4*)(prow + 4);
    prow += WW;

    // ---- R12-proven horizontal pass ----
    unsigned zl = (w2.x >> 5) & 0x01010101u, zh = (w2.y >> 5) & 0x01010101u;
    unsigned ml = (w2.x >> 6) & 0x01010101u, mh = (w2.y >> 6) & 0x01010101u;
    unsigned ql = (w2.x >> 7) & 0x01010101u, qh = (w2.y >> 7) & 0x01010101u;
    unsigned uLo = ml + ql + 2u * zl;
    unsigned uHi = mh + qh + 2u * zh;
    unsigned vLo = (ql + 0x01010101u) - ml;
    unsigned vHi = (qh + 0x01010101u) - mh;
    int zm1 = (int)((w1.y >> 29) & 1u), mm1 = (int)((w1.y >> 30) & 1u), qm1 = (int)(w1.y >> 31);
    int zp8 = (int)((w3.x >> 5) & 1u),  mp8 = (int)((w3.x >> 6) & 1u),  qp8 = (int)((w3.x >> 7) & 1u);
    int uM1 = mm1 + 2*zm1 + qm1, vM1 = qm1 - mm1 + 1;
    int uP8 = mp8 + 2*zp8 + qp8, vP8 = qp8 - mp8 + 1;

    int u0=UB(uLo,0), u1=UB(uLo,1), u2c=UB(uLo,2), u3=UB(uLo,3);
    int u4=UB(uHi,0), u5=UB(uHi,1), u6=UB(uHi,2), u7=UB(uHi,3);
    int v0=VB(vLo,0), v1=VB(vLo,1), v2c=VB(vLo,2), v3=VB(vLo,3);
    int v4=VB(vHi,0), v5=VB(vHi,1), v6=VB(vHi,2), v7=VB(vHi,3);
    int t0=(int)((w2.x>>5)&1u),  t1=(int)((w2.x>>13)&1u), t2=(int)((w2.x>>21)&1u), t3=(int)((w2.x>>29)&1u);
    int t4=(int)((w2.y>>5)&1u),  t5=(int)((w2.y>>13)&1u), t6=(int)((w2.y>>21)&1u), t7=(int)((w2.y>>29)&1u);

    unsigned p0 = (w0.x & 0x1F1F1F1Fu) + (w0.y & 0x1F1F1F1Fu)
                + (w1.x & 0x1F1F1F1Fu) + (w1.y & 0x1F1F1F1Fu)
                + (w2.x & 0x1F1F1F1Fu) + (w2.y & 0x1F1F1F1Fu)
                + (w3.x & 0x1F1F1F1Fu) + (w3.y & 0x1F1F1F1Fu);
    int sw = sum4b(p0) - (int)(w0.x & 0x1Fu);

    STEP(0, uM1, u1,  vM1, v0,  v1,  t0, pA.x);
    STEP(1, u0,  u2c, v0,  v1,  v2c, t1, pA.y);
    STEP(2, u1,  u3,  v1,  v2c, v3,  t2, pA.z);
    STEP(3, u2c, u4,  v2c, v3,  v4,  t3, pA.w);
    STEP(4, u3,  u5,  v3,  v4,  v5,  t4, pB.x);
    STEP(5, u4,  u6,  v4,  v5,  v6,  t5, pB.y);
    STEP(6, u5,  u7,  v5,  v6,  v7,  t6, pB.z);
    STEP(7, u6,  uP8, v6,  v7,  vP8, t7, pB.w);
    // ---- end horizontal pass ----

    unsigned ba = BYTE48(32 + E + j);   // row ys+j+16
    unsigned bs = BYTE48(1 + E + j);    // row ys+j-15
    cLo += SPL(ba) - SPL(bs);
    cHi += SPH(ba) - SPH(bs);
    bm = bz; bz = bq;
  }
}

// fully fused: wave = 64 byte-cols x 8 rows; bits window in registers via
// 3 coalesced uint4 loads; no vt8 intermediate, no LDS staging.
__global__ __launch_bounds__(256) void k_fused(const float* __restrict__ pred,
                                               const unsigned char* __restrict__ bitsT,
                                               double* __restrict__ acc) {
  __shared__ float s_red[4][3];
  int blk = blockIdx.x;            // 1024 = 64 img x 16 blockrows(32)
  int b   = blk >> 4;
  int tid = threadIdx.x;
  int wv  = tid >> 6, lane = tid & 63;
  int seg = (blk & 15) * 4 + wv;   // wave's 8-row segment
  int ys  = seg * 8;
  int s2  = seg >> 1;

  uint4 B0 = make_uint4(0u,0u,0u,0u), B2 = make_uint4(0u,0u,0u,0u);
  if (s2 >= 1)  B0 = *(const uint4*)(bitsT + (((size_t)(b * 32 + s2 - 1) * 64 + lane) << 4));
  uint4 B1      = *(const uint4*)(bitsT + (((size_t)(b * 32 + s2)     * 64 + lane) << 4));
  if (s2 <= 30) B2 = *(const uint4*)(bitsT + (((size_t)(b * 32 + s2 + 1) * 64 + lane) << 4));

  const float* prow = pred + (size_t)b * HWQ + (size_t)ys * WW + lane * 8;

  float a_c = 0.f, a_pt = 0.f, a_p = 0.f;
  if ((seg & 1) == 0) fused_rows<0>(B0, B1, B2, prow, lane, a_c, a_pt, a_p);
  else                fused_rows<8>(B0, B1, B2, prow, lane, a_c, a_pt, a_p);

  a_c = wredf(a_c); a_pt = wredf(a_pt); a_p = wredf(a_p);
  if (lane == 0) { s_red[wv][0] = a_c; s_red[wv][1] = a_pt; s_red[wv][2] = a_p; }
  __syncthreads();
  if (tid == 0) {
    float rc = 0, rpt = 0, rp = 0;
    for (int w = 0; w < 4; ++w) { rc += s_red[w][0]; rpt += s_red[w][1]; rp += s_red[w][2]; }
    atomicAdd(&acc[blk & 63],     (double)rc);
    atomicAdd(&acc[64 + 8*b + 0], (double)rpt);
    atomicAdd(&acc[64 + 8*b + 1], (double)rp);
  }
}

__global__ void k_final(const double* __restrict__ acc, const double* __restrict__ tpart,
                        float* __restrict__ out) {
  int t = threadIdx.x;  // 64 threads = 1 wave; t = image index
  double cs = acc[t];
  double TP = acc[64 + 8*t], Ps = acc[64 + 8*t + 1];
  double Ts = 0.0;
  for (int j = 0; j < 16; ++j) Ts += tpart[t * 16 + j];   // 16 k_bitsT blocks per image
  double FP = Ps - TP, FN = Ts - TP;
  double tv = (TP + 1e-6) / (TP + 0.3 * FP + 0.7 * FN + 1e-6);
  double om = 1.0 - tv;
  if (om < 0.0) om = 0.0;
  double term = pow(om, 1.0 / 1.33);
#pragma unroll
  for (int o = 32; o > 0; o >>= 1) {
    cs   += __shfl_down(cs, o, 64);
    term += __shfl_down(term, o, 64);
  }
  if (t == 0) {
    double ftl = term / 64.0;
    double n = (double)NTOT;
    out[0] = (float)(ftl - 0.6931471805599453 * cs / n);  // bce = -ln2 * log2(q)
  }
}

extern "C" void kernel_launch(void* const* d_in, const int* in_sizes, int n_in,
                              void* d_out, int out_size, void* d_ws, size_t ws_size,
                              hipStream_t stream) {
  (void)in_sizes; (void)n_in; (void)out_size; (void)ws_size;
  const float* pred = (const float*)d_in[0];
  const float* tgt  = (const float*)d_in[1];
  unsigned char* bitsT = (unsigned char*)d_ws;
  double* acc = (double*)((char*)d_ws + BITS_BYTES);
  double* tpart = acc + ACC_MAIN_DOUBLES;

  k_bitsT<<<1024, 256, 0, stream>>>(tgt, bitsT, acc, tpart);
  k_fused<<<BB * 16, 256, 0, stream>>>(pred, bitsT, acc);
  k_final<<<1, 64, 0, stream>>>(acc, tpart, (float*)d_out);
}

// Round 16
// 42.850 us; speedup vs baseline: 1.6351x; 1.0295x over previous
//
#include <hip/hip_runtime.h>
#include <math.h>

#define BB 64
#define HH 512
#define WW 512
#define HWQ (HH*WW)
#define NTOT ((size_t)BB*HWQ)

// ws layout:
//  [0, 2MB)   : TRANSPOSED bitmask: byte for (b, bytecol bc, row r) at
//               bitsT[((b*32 + (r>>4))*64 + bc)*16 + (r&15)]
//  then doubles:
//   [0..63]      a_c slots (k_fused atomics; zeroed by k_bitsT block 0)
//   [64+8b+0,1]  TP_b, sumP_b (k_fused atomics; zeroed by k_bitsT block 0)
//   [576+blk]    k_bitsT per-block t-count partials (plain stores)
#define BITS_BYTES (NTOT / 8)
#define ACC_MAIN_DOUBLES 576

#define FU(X) (__float_as_uint(X))

// target f32 -> transposed bitmask + per-block t-count. 1024 blocks. (R14 proven)
__global__ __launch_bounds__(256) void k_bitsT(const float* __restrict__ tgt,
                                               unsigned char* __restrict__ bitsT,
                                               double* __restrict__ accz,
                                               double* __restrict__ tpart) {
  if (blockIdx.x == 0) {
    for (int i = threadIdx.x; i < ACC_MAIN_DOUBLES; i += 256) accz[i] = 0.0;
  }
  int tid  = threadIdx.x;
  int bc   = tid & 63;
  int unit = blockIdx.x * 4 + (tid >> 6);   // 4096 units = 64 img x 64 rowgroups(8)
  int b    = unit >> 6;
  int rg   = unit & 63;
  int r0   = rg * 8;
  const float* timg = tgt + (size_t)b * HWQ;
  unsigned wlo = 0u, whi = 0u;
#pragma unroll
  for (int j = 0; j < 8; ++j) {
    const float* rp = timg + (size_t)(r0 + j) * WW + bc * 8;
    float4 a = *(const float4*)rp;
    float4 c = *(const float4*)(rp + 4);
    unsigned by = ((FU(a.x) >> 29) & 1u)        | (((FU(a.y) >> 29) & 1u) << 1)
                | (((FU(a.z) >> 29) & 1u) << 2) | (((FU(a.w) >> 29) & 1u) << 3)
                | (((FU(c.x) >> 29) & 1u) << 4) | (((FU(c.y) >> 29) & 1u) << 5)
                | (((FU(c.z) >> 29) & 1u) << 6) | (((FU(c.w) >> 29) & 1u) << 7);
    if (j < 4) wlo |= by << (8 * j); else whi |= by << (8 * (j - 4));
  }
  int rb = r0 >> 4, off = r0 & 15;
  *(uint2*)(bitsT + (((size_t)(b * 32 + rb) * 64 + bc) << 4) + off) = make_uint2(wlo, whi);

  int cnt = __popc(wlo) + __popc(whi);
#pragma unroll
  for (int o = 32; o > 0; o >>= 1) cnt += __shfl_down(cnt, o, 64);
  __shared__ int s_t[4];
  int wv = tid >> 6, lane = tid & 63;
  if (lane == 0) s_t[wv] = cnt;
  __syncthreads();
  if (tid == 0) tpart[blockIdx.x] = (double)(s_t[0] + s_t[1] + s_t[2] + s_t[3]);
}

// nibble -> byte-lane spread (bit j of nibble -> byte j)
#define SPL(B) ((((B) & 0xFu) * 0x00204081u) & 0x01010101u)
#define SPH(B) ((((B) >> 4)   * 0x00204081u) & 0x01010101u)

// byte K (0..47) of the 3-block register window B0,B1,B2 (K compile-time)
#define W48(K) ((K)<16 ? (((K)&15)<8 ? (((K)&15)<4?B0.x:B0.y) : (((K)&15)<12?B0.z:B0.w)) \
              : (K)<32 ? (((K)&15)<8 ? (((K)&15)<4?B1.x:B1.y) : (((K)&15)<12?B1.z:B1.w)) \
                       : (((K)&15)<8 ? (((K)&15)<4?B2.x:B2.y) : (((K)&15)<12?B2.z:B2.w)))
#define BYTE48(K) ((W48(K) >> (((K)&3)*8)) & 0xFFu)

__device__ inline float wredf(float v) {
#pragma unroll
  for (int o = 32; o > 0; o >>= 1) v += __shfl_down(v, o, 64);
  return v;
}

__device__ inline int sum4b(unsigned x) {     // sum of the 4 bytes
  unsigned t = (x & 0x00FF00FFu) + ((x >> 8) & 0x00FF00FFu);
  return (int)((t + (t >> 16)) & 0xFFFFu);
}

// window byte I (0..39) <-> col x0-16+I ; I compile-time -> folds to one bfe
#define VTW(I) ((I) < 8  ? (((I)&7) < 4 ? c0x : c0y) : \
                (I) < 16 ? (((I)&7) < 4 ? c1x : c1y) : \
                (I) < 24 ? (((I)&7) < 4 ? c2x : c2y) : \
                (I) < 32 ? (((I)&7) < 4 ? c3x : c3y) : \
                           (((I)&7) < 4 ? c4x : c4y))
#define BGET5(I) ((int)((VTW(I) >> (((I)&3)*8)) & 31u))   // 5-bit vsum field

// one output column (identical math to R8/R12/R15, which passed)
#define STEP(C, UM, UP, VM, VC, VP, TCI, PV) do {                     \
    int gx = (UP) - (UM);                                             \
    int gy = (VM) + 2*(VC) + (VP) - 4;                                \
    float tb = __builtin_amdgcn_sqrtf((float)(gx*gx + gy*gy) + 1e-12f); \
    float qq = (TCI) ? (PV) : 1.f - (PV);                             \
    float lg = __log2f(qq);                                           \
    int   di = (TCI) ? (961 - sw) : sw;                               \
    float wgt = fmaf(5.f, tb, fmaf(1.5608741e-3f, (float)di, 0.8f));  \
    a_c = fmaf(wgt, lg, a_c);                                         \
    a_pt += (TCI) ? (PV) : 0.f;                                       \
    a_p  += (PV);                                                     \
    sw += BGET5((C)+32) - BGET5((C)+1);                               \
  } while (0)

#define UB(W,J) ((int)(((W) >> (8*(J))) & 7u))            // u byte (0..4)
#define VB(W,J) ((int)(((W) >> (8*(J))) & 3u))            // v+1 byte (0..2)

#define SHFLS(DX, DY, SX, SY)                               \
    DX##1x = __shfl_up(SX, 1, 64);  DY##1y = __shfl_up(SY, 1, 64);  \
    DX##0x = __shfl_up(SX, 2, 64);  DY##0y = __shfl_up(SY, 2, 64);  \
    DX##3x = __shfl_down(SX, 1, 64); DY##3y = __shfl_down(SY, 1, 64); \
    DX##4x = __shfl_down(SX, 2, 64); DY##4y = __shfl_down(SY, 2, 64)

// fused body, software-pipelined: at iter j, next row's pred load + window
// shfls are issued BEFORE row j's STEP block consumes the current ones.
template<int E>
__device__ __forceinline__ void fused_rows(uint4 B0, uint4 B1, uint4 B2,
                                           const float* __restrict__ prow,
                                           int lane,
                                           float& a_c, float& a_pt, float& a_p) {
  // two-chain 31-tap init
  unsigned cLoA = 0u, cHiA = 0u, cLoB = 0u, cHiB = 0u;
#pragma unroll
  for (int j = -15; j <= 13; j += 2) {
    unsigned ba_ = BYTE48(j + 16 + E);
    unsigned bb_ = BYTE48(j + 17 + E);
    cLoA += SPL(ba_); cHiA += SPH(ba_);
    cLoB += SPL(bb_); cHiB += SPH(bb_);
  }
  { unsigned bl_ = BYTE48(31 + E); cLoA += SPL(bl_); cHiA += SPH(bl_); }
  unsigned cLo = cLoA + cLoB, cHi = cHiA + cHiB;

  unsigned bm = BYTE48(15 + E);   // row ys-1 (OOB auto-zero via zeroed blocks)
  unsigned bz = BYTE48(16 + E);   // row ys
  unsigned bq = BYTE48(17 + E);   // row ys+1

  // row 0: own window + shfls + pred
  unsigned w2x = cLo | (SPL(bz) << 5) | (SPL(bm) << 6) | (SPL(bq) << 7);
  unsigned w2y = cHi | (SPH(bz) << 5) | (SPH(bm) << 6) | (SPH(bq) << 7);
  unsigned w1x, w0x, w3x, w4x, w1y, w0y, w3y, w4y;
  SHFLS(w, w, w2x, w2y);
  float4 pA = *(const float4*)prow;
  float4 pB = *(const float4*)(prow + 4);

#pragma unroll
  for (int j = 0; j < 8; ++j) {
    // ---- prefetch next row (pred + window shfls) ----
    unsigned nw2x = 0u, nw2y = 0u;
    unsigned nw1x = 0u, nw0x = 0u, nw3x = 0u, nw4x = 0u;
    unsigned nw1y = 0u, nw0y = 0u, nw3y = 0u, nw4y = 0u;
    float4 nA = make_float4(0, 0, 0, 0), nB = make_float4(0, 0, 0, 0);
    if (j < 7) {
      nA = *(const float4*)(prow + WW);
      nB = *(const float4*)(prow + WW + 4);
      unsigned ba = BYTE48(32 + E + j);   // row ys+j+16 enters box
      unsigned bs = BYTE48(1 + E + j);    // row ys+j-15 leaves box
      cLo += SPL(ba) - SPL(bs);
      cHi += SPH(ba) - SPH(bs);
      bm = bz; bz = bq; bq = BYTE48(18 + E + j);
      nw2x = cLo | (SPL(bz) << 5) | (SPL(bm) << 6) | (SPL(bq) << 7);
      nw2y = cHi | (SPH(bz) << 5) | (SPH(bm) << 6) | (SPH(bq) << 7);
      SHFLS(nw, nw, nw2x, nw2y);
    }

    // ---- current row: mask edges, then STEP ----
    unsigned c0x = (lane < 2)  ? 0u : w0x, c0y = (lane < 2)  ? 0u : w0y;
    unsigned c1x = (lane < 1)  ? 0u : w1x, c1y = (lane < 1)  ? 0u : w1y;
    unsigned c2x = w2x,                    c2y = w2y;
    unsigned c3x = (lane > 62) ? 0u : w3x, c3y = (lane > 62) ? 0u : w3y;
    unsigned c4x = (lane > 61) ? 0u : w4x, c4y = (lane > 61) ? 0u : w4y;

    unsigned zl = (c2x >> 5) & 0x01010101u, zh = (c2y >> 5) & 0x01010101u;
    unsigned ml = (c2x >> 6) & 0x01010101u, mh = (c2y >> 6) & 0x01010101u;
    unsigned ql = (c2x >> 7) & 0x01010101u, qh = (c2y >> 7) & 0x01010101u;
    unsigned uLo = ml + ql + 2u * zl;
    unsigned uHi = mh + qh + 2u * zh;
    unsigned vLo = (ql + 0x01010101u) - ml;
    unsigned vHi = (qh + 0x01010101u) - mh;
    int zm1 = (int)((c1y >> 29) & 1u), mm1 = (int)((c1y >> 30) & 1u), qm1 = (int)(c1y >> 31);
    int zp8 = (int)((c3x >> 5) & 1u),  mp8 = (int)((c3x >> 6) & 1u),  qp8 = (int)((c3x >> 7) & 1u);
    int uM1 = mm1 + 2*zm1 + qm1, vM1 = qm1 - mm1 + 1;
    int uP8 = mp8 + 2*zp8 + qp8, vP8 = qp8 - mp8 + 1;

    int u0=UB(uLo,0), u1=UB(uLo,1), u2c=UB(uLo,2), u3=UB(uLo,3);
    int u4=UB(uHi,0), u5=UB(uHi,1), u6=UB(uHi,2), u7=UB(uHi,3);
    int v0=VB(vLo,0), v1=VB(vLo,1), v2c=VB(vLo,2), v3=VB(vLo,3);
    int v4=VB(vHi,0), v5=VB(vHi,1), v6=VB(vHi,2), v7=VB(vHi,3);
    int t0=(int)((c2x>>5)&1u),  t1=(int)((c2x>>13)&1u), t2=(int)((c2x>>21)&1u), t3=(int)((c2x>>29)&1u);
    int t4=(int)((c2y>>5)&1u),  t5=(int)((c2y>>13)&1u), t6=(int)((c2y>>21)&1u), t7=(int)((c2y>>29)&1u);

    unsigned p0 = (c0x & 0x1F1F1F1Fu) + (c0y & 0x1F1F1F1Fu)
                + (c1x & 0x1F1F1F1Fu) + (c1y & 0x1F1F1F1Fu)
                + (c2x & 0x1F1F1F1Fu) + (c2y & 0x1F1F1F1Fu)
                + (c3x & 0x1F1F1F1Fu) + (c3y & 0x1F1F1F1Fu);
    int sw = sum4b(p0) - (int)(c0x & 0x1Fu);

    STEP(0, uM1, u1,  vM1, v0,  v1,  t0, pA.x);
    STEP(1, u0,  u2c, v0,  v1,  v2c, t1, pA.y);
    STEP(2, u1,  u3,  v1,  v2c, v3,  t2, pA.z);
    STEP(3, u2c, u4,  v2c, v3,  v4,  t3, pA.w);
    STEP(4, u3,  u5,  v3,  v4,  v5,  t4, pB.x);
    STEP(5, u4,  u6,  v4,  v5,  v6,  t5, pB.y);
    STEP(6, u5,  u7,  v5,  v6,  v7,  t6, pB.z);
    STEP(7, u6,  uP8, v6,  v7,  vP8, t7, pB.w);

    // ---- rotate pipeline ----
    w2x = nw2x; w2y = nw2y;
    w0x = nw0x; w0y = nw0y; w1x = nw1x; w1y = nw1y;
    w3x = nw3x; w3y = nw3y; w4x = nw4x; w4y = nw4y;
    pA = nA; pB = nB;
    prow += WW;
  }
}

// fully fused: wave = 64 byte-cols x 8 rows; bits window in registers via
// 3 coalesced uint4 loads; XCD-grouped work mapping for bits L2 locality.
__global__ __launch_bounds__(256) void k_fused(const float* __restrict__ pred,
                                               const unsigned char* __restrict__ bitsT,
                                               double* __restrict__ acc) {
  __shared__ float s_red[4][3];
  // XCD grouping: XCD x (= blockIdx%8) handles wids x*128..x*128+127 = 8 images
  int wid = (blockIdx.x & 7) * 128 + (blockIdx.x >> 3);   // bijective, 1024 blocks
  int b   = wid >> 4;
  int tid = threadIdx.x;
  int wv  = tid >> 6, lane = tid & 63;
  int seg = (wid & 15) * 4 + wv;   // wave's 8-row segment (0..63)
  int ys  = seg * 8;
  int s2  = seg >> 1;

  uint4 B0 = make_uint4(0u,0u,0u,0u), B2 = make_uint4(0u,0u,0u,0u);
  if (s2 >= 1)  B0 = *(const uint4*)(bitsT + (((size_t)(b * 32 + s2 - 1) * 64 + lane) << 4));
  uint4 B1      = *(const uint4*)(bitsT + (((size_t)(b * 32 + s2)     * 64 + lane) << 4));
  if (s2 <= 30) B2 = *(const uint4*)(bitsT + (((size_t)(b * 32 + s2 + 1) * 64 + lane) << 4));

  const float* prow = pred + (size_t)b * HWQ + (size_t)ys * WW + lane * 8;

  float a_c = 0.f, a_pt = 0.f, a_p = 0.f;
  if ((seg & 1) == 0) fused_rows<0>(B0, B1, B2, prow, lane, a_c, a_pt, a_p);
  else                fused_rows<8>(B0, B1, B2, prow, lane, a_c, a_pt, a_p);

  a_c = wredf(a_c); a_pt = wredf(a_pt); a_p = wredf(a_p);
  if (lane == 0) { s_red[wv][0] = a_c; s_red[wv][1] = a_pt; s_red[wv][2] = a_p; }
  __syncthreads();
  if (tid == 0) {
    float rc = 0, rpt = 0, rp = 0;
    for (int w = 0; w < 4; ++w) { rc += s_red[w][0]; rpt += s_red[w][1]; rp += s_red[w][2]; }
    atomicAdd(&acc[wid & 63],     (double)rc);
    atomicAdd(&acc[64 + 8*b + 0], (double)rpt);
    atomicAdd(&acc[64 + 8*b + 1], (double)rp);
  }
}

__global__ void k_final(const double* __restrict__ acc, const double* __restrict__ tpart,
                        float* __restrict__ out) {
  int t = threadIdx.x;  // 64 threads = 1 wave; t = image index
  double cs = acc[t];
  double TP = acc[64 + 8*t], Ps = acc[64 + 8*t + 1];
  double Ts = 0.0;
  for (int j = 0; j < 16; ++j) Ts += tpart[t * 16 + j];   // 16 k_bitsT blocks per image
  double FP = Ps - TP, FN = Ts - TP;
  double tv = (TP + 1e-6) / (TP + 0.3 * FP + 0.7 * FN + 1e-6);
  double om = 1.0 - tv;
  if (om < 0.0) om = 0.0;
  double term = pow(om, 1.0 / 1.33);
#pragma unroll
  for (int o = 32; o > 0; o >>= 1) {
    cs   += __shfl_down(cs, o, 64);
    term += __shfl_down(term, o, 64);
  }
  if (t == 0) {
    double ftl = term / 64.0;
    double n = (double)NTOT;
    out[0] = (float)(ftl - 0.6931471805599453 * cs / n);  // bce = -ln2 * log2(q)
  }
}

extern "C" void kernel_launch(void* const* d_in, const int* in_sizes, int n_in,
                              void* d_out, int out_size, void* d_ws, size_t ws_size,
                              hipStream_t stream) {
  (void)in_sizes; (void)n_in; (void)out_size; (void)ws_size;
  const float* pred = (const float*)d_in[0];
  const float* tgt  = (const float*)d_in[1];
  unsigned char* bitsT = (unsigned char*)d_ws;
  double* acc = (double*)((char*)d_ws + BITS_BYTES);
  double* tpart = acc + ACC_MAIN_DOUBLES;

  k_bitsT<<<1024, 256, 0, stream>>>(tgt, bitsT, acc, tpart);
  k_fused<<<BB * 16, 256, 0, stream>>>(pred, bitsT, acc);
  k_final<<<1, 64, 0, stream>>>(acc, tpart, (float*)d_out);
}